// Round 1
// baseline (272.948 us; speedup 1.0000x reference)
//
#include <hip/hip_runtime.h>
#include <math.h>

// Problem shape (from reference setup_inputs): B=4, H=320, W=320.
#define B_ 4
#define H_ 320
#define W_ 320
#define N_TOTAL (B_ * H_ * W_)

// Kernel 1: vertical 1D squared distance per column.
// g2[b,h,w] = min over h' with seed(b,h',w) of (h-h')^2, sentinel 1e12 if column empty.
__global__ void edt_vertical(const int* __restrict__ tgt, float* __restrict__ g2) {
    int t = blockIdx.x * blockDim.x + threadIdx.x;
    if (t >= B_ * W_) return;
    int b = t / W_;
    int w = t - b * W_;
    const int* col = tgt + (size_t)b * H_ * W_ + w;
    float* gcol = g2 + (size_t)b * H_ * W_ + w;

    // downward sweep: distance to nearest seed at or above
    int last = -1;
    for (int h = 0; h < H_; ++h) {
        if (col[(size_t)h * W_] > 0) last = h;
        float d = (last >= 0) ? (float)(h - last) : 1e6f;
        gcol[(size_t)h * W_] = d;
    }
    // upward sweep: min with distance to nearest seed at or below; square
    int next = -1;
    for (int h = H_ - 1; h >= 0; --h) {
        if (col[(size_t)h * W_] > 0) next = h;
        float d = (next >= 0) ? (float)(next - h) : 1e6f;
        float m = fminf(d, gcol[(size_t)h * W_]);
        gcol[(size_t)h * W_] = m * m;
    }
}

// Kernel 2: per-row horizontal min envelope (brute force over W), fused with
// sigmoid + loss terms, block-reduced into double accumulators.
__global__ __launch_bounds__(W_) void row_min_loss(const float* __restrict__ g2,
                                                   const float* __restrict__ logits,
                                                   double* __restrict__ acc) {
    int row = blockIdx.x;       // 0 .. B*H-1
    int wo = threadIdx.x;       // 0 .. W-1

    __shared__ float sg[W_];
    const float* grow = g2 + (size_t)row * W_;
    sg[wo] = grow[wo];
    __syncthreads();

    float best = 1e30f;
    float wof = (float)wo;
#pragma unroll 8
    for (int wi = 0; wi < W_; ++wi) {
        float off = wof - (float)wi;
        best = fminf(best, sg[wi] + off * off);   // all lanes read same sg[wi] -> broadcast
    }

    float d = sqrtf(best);
    float x = logits[(size_t)row * W_ + wo];
    float p = 1.0f / (1.0f + expf(-x));
    float v1 = p * d;          // contributes to mean(probs * dist)
    float v2 = 1.0f - p;       // contributes to mean(1 - probs)

    // wave-level (64-lane) reduction
    for (int off = 32; off > 0; off >>= 1) {
        v1 += __shfl_down(v1, off, 64);
        v2 += __shfl_down(v2, off, 64);
    }
    if ((threadIdx.x & 63) == 0) {
        atomicAdd(&acc[0], (double)v1);
        atomicAdd(&acc[1], (double)v2);
    }
}

// Kernel 3: finalize scalar.
__global__ void finalize_loss(const double* __restrict__ acc, float* __restrict__ out) {
    const double invN = 1.0 / (double)N_TOTAL;
    out[0] = (float)(acc[0] * invN + 1.0 * acc[1] * invN);  // LAMBDA = 1.0
}

extern "C" void kernel_launch(void* const* d_in, const int* in_sizes, int n_in,
                              void* d_out, int out_size, void* d_ws, size_t ws_size,
                              hipStream_t stream) {
    const float* logits = (const float*)d_in[0];
    const int* targets  = (const int*)d_in[1];
    float* out = (float*)d_out;

    // workspace layout: g2 [B*H*W floats], then 2 doubles (256B aligned)
    float* g2 = (float*)d_ws;
    size_t g2_bytes = (size_t)N_TOTAL * sizeof(float);
    size_t acc_off = (g2_bytes + 255) & ~(size_t)255;
    double* acc = (double*)((char*)d_ws + acc_off);

    hipMemsetAsync(acc, 0, 2 * sizeof(double), stream);

    edt_vertical<<<(B_ * W_ + 255) / 256, 256, 0, stream>>>(targets, g2);
    row_min_loss<<<B_ * H_, W_, 0, stream>>>(g2, logits, acc);
    finalize_loss<<<1, 1, 0, stream>>>(acc, out);
}

// Round 2
// 65.121 us; speedup vs baseline: 4.1914x; 4.1914x over previous
//
#include <hip/hip_runtime.h>
#include <math.h>

// Problem shape (from reference setup_inputs): B=4, H=320, W=320.
#define B_ 4
#define H_ 320
#define W_ 320
#define N_TOTAL (B_ * H_ * W_)     // 409600
#define BLOCK 256
#define NBLK (N_TOTAL / BLOCK)     // 1600 exactly (409600 = 1600*256)

// Fused kernel: exact per-pixel EDT via outward Chebyshev-ring scan
// (exact: keep scanning rings until r^2 >= best2, so every candidate that
// could beat the incumbent is examined), fused with sigmoid + both loss
// terms, block-reduced to one double2 partial per block (no atomics).
// With 50%-dense random targets the expected scan is ~5 pixels/thread.
__global__ __launch_bounds__(BLOCK) void fused_edt_loss(
        const float* __restrict__ logits,
        const int* __restrict__ tgt,
        double* __restrict__ partial /* [NBLK*2] */) {
    int idx = blockIdx.x * BLOCK + threadIdx.x;   // always < N_TOTAL (exact grid)
    int b = idx / (H_ * W_);
    int rem = idx - b * (H_ * W_);
    int h = rem / W_;
    int w = rem - h * W_;
    const int* __restrict__ img = tgt + b * (H_ * W_);

    int best2 = 0x7fffffff;
    if (img[h * W_ + w] > 0) best2 = 0;   // ring r = 0

    for (int r = 1; r < H_ + W_; ++r) {   // bound guarantees termination
        int r2 = r * r;
        if (r2 >= best2) break;           // no further ring can improve
        int hlo = h - r, hhi = h + r;
        int wlo = w - r, whi = w + r;
        int wl = wlo > 0 ? wlo : 0;
        int wr = whi < (W_ - 1) ? whi : (W_ - 1);
        if (hlo >= 0) {                   // top edge of ring: dh = r
            const int* rowp = img + hlo * W_;
            for (int ww = wl; ww <= wr; ++ww)
                if (rowp[ww] > 0) {
                    int dw = ww - w;
                    int d2 = r2 + dw * dw;
                    best2 = d2 < best2 ? d2 : best2;
                }
        }
        if (hhi < H_) {                   // bottom edge: dh = r
            const int* rowp = img + hhi * W_;
            for (int ww = wl; ww <= wr; ++ww)
                if (rowp[ww] > 0) {
                    int dw = ww - w;
                    int d2 = r2 + dw * dw;
                    best2 = d2 < best2 ? d2 : best2;
                }
        }
        int hl = (hlo + 1) > 0 ? (hlo + 1) : 0;
        int hr = (hhi - 1) < (H_ - 1) ? (hhi - 1) : (H_ - 1);
        if (wlo >= 0) {                   // left edge: dw = r
            for (int hh = hl; hh <= hr; ++hh)
                if (img[hh * W_ + wlo] > 0) {
                    int dh = hh - h;
                    int d2 = dh * dh + r2;
                    best2 = d2 < best2 ? d2 : best2;
                }
        }
        if (whi < W_) {                   // right edge: dw = r
            for (int hh = hl; hh <= hr; ++hh)
                if (img[hh * W_ + whi] > 0) {
                    int dh = hh - h;
                    int d2 = dh * dh + r2;
                    best2 = d2 < best2 ? d2 : best2;
                }
        }
    }

    float d = sqrtf((float)best2);        // exact: best2 < 2^24, integer-exact in fp32
    float x = logits[idx];
    float p = 1.0f / (1.0f + expf(-x));
    double v1 = (double)(p * d);          // term: mean(probs * dist)
    double v2 = (double)(1.0f - p);       // term: mean(1 - probs), LAMBDA = 1

    // wave(64) shuffle reduce, then cross-wave LDS reduce — zero atomics
    for (int off = 32; off > 0; off >>= 1) {
        v1 += __shfl_down(v1, off, 64);
        v2 += __shfl_down(v2, off, 64);
    }
    __shared__ double s1[BLOCK / 64], s2[BLOCK / 64];
    int wave = threadIdx.x >> 6;
    if ((threadIdx.x & 63) == 0) { s1[wave] = v1; s2[wave] = v2; }
    __syncthreads();
    if (threadIdx.x == 0) {
        partial[2 * blockIdx.x]     = s1[0] + s1[1] + s1[2] + s1[3];
        partial[2 * blockIdx.x + 1] = s2[0] + s2[1] + s2[2] + s2[3];
    }
}

// One-block final reduction of the 1600 double2 partials.
__global__ __launch_bounds__(256) void final_reduce(
        const double* __restrict__ partial, float* __restrict__ out) {
    double v1 = 0.0, v2 = 0.0;
    for (int i = threadIdx.x; i < NBLK; i += 256) {
        v1 += partial[2 * i];
        v2 += partial[2 * i + 1];
    }
    for (int off = 32; off > 0; off >>= 1) {
        v1 += __shfl_down(v1, off, 64);
        v2 += __shfl_down(v2, off, 64);
    }
    __shared__ double s1[4], s2[4];
    int wave = threadIdx.x >> 6;
    if ((threadIdx.x & 63) == 0) { s1[wave] = v1; s2[wave] = v2; }
    __syncthreads();
    if (threadIdx.x == 0) {
        double a = s1[0] + s1[1] + s1[2] + s1[3];
        double c = s2[0] + s2[1] + s2[2] + s2[3];
        out[0] = (float)((a + c) / (double)N_TOTAL);
    }
}

extern "C" void kernel_launch(void* const* d_in, const int* in_sizes, int n_in,
                              void* d_out, int out_size, void* d_ws, size_t ws_size,
                              hipStream_t stream) {
    const float* logits = (const float*)d_in[0];
    const int* targets  = (const int*)d_in[1];
    float* out = (float*)d_out;
    double* partial = (double*)d_ws;   // NBLK*2 doubles = 25.6 KB; fully
                                       // rewritten every call (no memset needed)

    fused_edt_loss<<<NBLK, BLOCK, 0, stream>>>(logits, targets, partial);
    final_reduce<<<1, 256, 0, stream>>>(partial, out);
}